// Round 18
// baseline (6049.456 us; speedup 1.0000x reference)
//
#include <hip/hip_runtime.h>
#include <stdint.h>

// ---------- types ----------
typedef short sv8 __attribute__((ext_vector_type(8)));      // 8 x bf16 raw
typedef float fv4 __attribute__((ext_vector_type(4)));      // MFMA acc
typedef uint32_t u32x4 __attribute__((ext_vector_type(4))); // asm operand
typedef uint32_t u32x2 __attribute__((ext_vector_type(2))); // asm operand

__device__ __forceinline__ uint16_t f2bf(float f) {
    uint32_t u = __builtin_bit_cast(uint32_t, f);
    u += 0x7FFFu + ((u >> 16) & 1u);
    return (uint16_t)(u >> 16);
}
__device__ __forceinline__ float bf2f(uint16_t h) {
    uint32_t u = ((uint32_t)h) << 16;
    return __builtin_bit_cast(float, u);
}
__device__ __forceinline__ void split4(float4 f, ushort4& h, ushort4& l) {
    h.x = f2bf(f.x); l.x = f2bf(f.x - bf2f(h.x));
    h.y = f2bf(f.y); l.y = f2bf(f.y - bf2f(h.y));
    h.z = f2bf(f.z); l.z = f2bf(f.z - bf2f(h.z));
    h.w = f2bf(f.w); l.w = f2bf(f.w - bf2f(h.w));
}
// fast gates (finite-in -> finite-out)
__device__ __forceinline__ float fsig(float x)  { return 1.f / (1.f + __expf(-x)); }
__device__ __forceinline__ float ftanh(float x) { return 1.f - 2.f / (__expf(2.f * x) + 1.f); }

// coherent (MALL-point) loads
__device__ __forceinline__ u32x4 load16_cc(const void* p) {
    u32x4 r;
    asm volatile("global_load_dwordx4 %0, %1, off sc0 sc1" : "=v"(r) : "v"(p) : "memory");
    return r;
}
__device__ __forceinline__ u32x2 load8_cc(const void* p) {
    u32x2 r;
    asm volatile("global_load_dwordx2 %0, %1, off sc0 sc1" : "=v"(r) : "v"(p) : "memory");
    return r;
}
// atomic stores: performed AT the MALL -> fast global visibility
__device__ __forceinline__ void atom8_st(void* p, u32x2 v) {
    asm volatile("global_atomic_swap_x2 %0, %1, off" :: "v"(p), "v"(v) : "memory");
}
__device__ __forceinline__ void atom4_st(void* p, uint32_t v) {
    asm volatile("global_atomic_swap %0, %1, off" :: "v"(p), "v"(v) : "memory");
}

// ---------- sizes ----------
#define TT     1024
#define DD     512
#define NN     2048
#define TCH    128           // timesteps per chunk
#define NCHUNK 8
#define NREG   8             // h region ring (16KB regions, per group)
#define REGB   16384         // region bytes (16 rows x 512 u x 2B)
#define NG     4             // row groups
#define GW     16            // WGs per group

// =====================================================================
// Prep: kernel [512][2048] fp32 -> transposed bf16 hi/lo  BT[2048][512]
// =====================================================================
__global__ void prep_split_b(const float* __restrict__ kern,
                             uint16_t* __restrict__ bth, uint16_t* __restrict__ btl) {
    int tid = blockIdx.x * 256 + threadIdx.x;
    if (tid >= DD * NN) return;
    int k = tid >> 11;
    int n = tid & (NN - 1);
    float v = kern[tid];
    uint16_t h = f2bf(v);
    bth[n * DD + k] = h;
    btl[n * DD + k] = f2bf(v - bf2f(h));
}

// =====================================================================
// Prep: recurrent_kernel -> per-lane MFMA B-fragment order, split hi/lo
// =====================================================================
__global__ void prep_rk(const float* __restrict__ rk,
                        uint16_t* __restrict__ rkh, uint16_t* __restrict__ rkl) {
    int tid = blockIdx.x * 256 + threadIdx.x;
    if (tid >= 128 * 16 * 64 * 8) return;
    int j = tid & 7, lane = (tid >> 3) & 63, kt = (tid >> 9) & 15, g = tid >> 13;
    int lq = lane >> 4, c = lane & 15;
    int k = kt * 32 + lq * 8 + j;
    int colg = (c >> 2) * 512 + g * 4 + (c & 3);
    float v = rk[(size_t)k * NN + colg];
    uint16_t h = f2bf(v);
    rkh[tid] = h;
    rkl[tid] = f2bf(v - bf2f(h));
}

// =====================================================================
// GEMM tile body (shared by gemm_xz and fused gemm role).
// =====================================================================
__device__ __forceinline__ void gemm_tile(
    const float* __restrict__ tx, int t0,
    const uint16_t* __restrict__ Bth, const uint16_t* __restrict__ Btl,
    float* __restrict__ xz, uint16_t* sb, int t256, int btile, int n0, int act) {
    int lane = t256 & 63, w = t256 >> 6;
    int wm = (w >> 1) * 64, wn = (w & 1) * 64;
    int srow = t256 >> 1, scol = (t256 & 1) * 16;
    fv4 acc[4][4];
#pragma unroll
    for (int q = 0; q < 4; q++)
#pragma unroll
        for (int r = 0; r < 4; r++) acc[q][r] = (fv4){0.f, 0.f, 0.f, 0.f};

    const float* abase = tx + ((size_t)btile * TT + t0 + srow) * DD + scol;

    for (int k0 = 0; k0 < DD; k0 += 32) {
        float4 f0, f1, f2, f3;
        uint4 b0, b1, c0, c1;
        if (act) {
            const float4* A4 = (const float4*)(abase + k0);
            f0 = A4[0]; f1 = A4[1]; f2 = A4[2]; f3 = A4[3];
            const uint16_t* pb  = Bth + (size_t)(n0 + srow) * DD + k0 + scol;
            const uint16_t* pbl = Btl + (size_t)(n0 + srow) * DD + k0 + scol;
            b0 = *(const uint4*)pb;  b1 = *(const uint4*)(pb + 8);
            c0 = *(const uint4*)pbl; c1 = *(const uint4*)(pbl + 8);
        }
        __syncthreads();
        if (act) {
            union { ushort4 v4[4]; uint4 q[2]; } H, L;
            split4(f0, H.v4[0], L.v4[0]);
            split4(f1, H.v4[1], L.v4[1]);
            split4(f2, H.v4[2], L.v4[2]);
            split4(f3, H.v4[3], L.v4[3]);
            *(uint4*)&sb[srow * 32 + scol]            = H.q[0];
            *(uint4*)&sb[srow * 32 + scol + 8]        = H.q[1];
            *(uint4*)&sb[4096 + srow * 32 + scol]     = L.q[0];
            *(uint4*)&sb[4096 + srow * 32 + scol + 8] = L.q[1];
            *(uint4*)&sb[8192 + srow * 32 + scol]     = b0;
            *(uint4*)&sb[8192 + srow * 32 + scol + 8] = b1;
            *(uint4*)&sb[12288 + srow * 32 + scol]    = c0;
            *(uint4*)&sb[12288 + srow * 32 + scol + 8]= c1;
        }
        __syncthreads();
        sv8 ah[4], al[4], bh[4], bl[4];
#pragma unroll
        for (int q = 0; q < 4; q++) {
            int ra = (wm + q * 16 + (lane & 15)) * 32 + (lane >> 4) * 8;
            ah[q] = *(const sv8*)&sb[ra];
            al[q] = *(const sv8*)&sb[4096 + ra];
        }
#pragma unroll
        for (int r = 0; r < 4; r++) {
            int rb = (wn + r * 16 + (lane & 15)) * 32 + (lane >> 4) * 8;
            bh[r] = *(const sv8*)&sb[8192 + rb];
            bl[r] = *(const sv8*)&sb[12288 + rb];
        }
#pragma unroll
        for (int q = 0; q < 4; q++)
#pragma unroll
            for (int r = 0; r < 4; r++) {
                acc[q][r] = __builtin_amdgcn_mfma_f32_16x16x32_bf16(ah[q], bh[r], acc[q][r], 0, 0, 0);
                acc[q][r] = __builtin_amdgcn_mfma_f32_16x16x32_bf16(ah[q], bl[r], acc[q][r], 0, 0, 0);
                acc[q][r] = __builtin_amdgcn_mfma_f32_16x16x32_bf16(al[q], bh[r], acc[q][r], 0, 0, 0);
            }
    }
    if (act) {
#pragma unroll
        for (int q = 0; q < 4; q++)
#pragma unroll
            for (int r = 0; r < 4; r++) {
                int tl0 = wm + q * 16 + ((lane >> 4) * 4);
                int ncol = n0 + wn + r * 16 + (lane & 15);
                int gate = ncol >> 9, uu = ncol & 511;
                int cil = gate * 4 + (uu & 3);
                int g = uu >> 2;
#pragma unroll
                for (int e = 0; e < 4; e++) {
                    size_t idx = (((size_t)(g * 64 + btile) * TCH + (tl0 + e)) << 4) + cil;
                    xz[idx] = acc[q][r][e];
                }
            }
    }
}

// =====================================================================
// Phase 1 standalone: xz for one chunk.  Grid 1024 x 256.
// =====================================================================
__global__ __launch_bounds__(256, 2) void gemm_xz(
    const float* __restrict__ tx, int t0,
    const uint16_t* __restrict__ Bth, const uint16_t* __restrict__ Btl,
    float* __restrict__ xz) {
    __shared__ __align__(16) uint16_t sb[16384];   // 32KB
    gemm_tile(tx, t0, Bth, Btl, xz, sb, threadIdx.x,
              blockIdx.x >> 4, (blockIdx.x & 15) * 128, 1);
}

// =====================================================================
// LSTM recurrence body, 4 row-groups + PER-WAVE stamps, SAFE poll (r18):
// = r16 structure with the WG join barrier (A) removed:
// - producer wave: 16 h-atomics -> own-wave vmcnt(0) -> lane0 stamps
//   slot cg*8+w (per-wave; no cross-wave rendezvous)
// - stamps: 128 slots/group-region packed 2-per-64B-line (64 lines);
//   consumer lane l polls line l with ONE dwordx2; vmcnt(0) EVERY
//   iteration (no in-flight loads may cross a break — r17 lesson)
// - WAR safety via stamp transitivity: stamp t+1 implies that wave's
//   payload loads (vmcnt-drained) and LDS reads (program order) of
//   step t are complete; passing poll t+1 implies same for all mates.
// =====================================================================
__device__ __forceinline__ void lstm_body(
    const uint16_t* __restrict__ rkh, const uint16_t* __restrict__ rkl,
    const float* __restrict__ bias, const float* __restrict__ xz,
    char* __restrict__ hbuf, uint32_t* __restrict__ rdy,
    float* __restrict__ cstate, float* __restrict__ hlast, int gbase,
    uint16_t* ls /* 8192 u16 = 16KB */, int wg, int tid) {
    int hf = wg >> 4, cg = wg & 15;
    int lane = tid & 63, w = tid >> 6;      // 8 waves
    int c = lane & 15, lq = lane >> 4;
    int g = cg * 8 + w;                      // u-quad 0..127
    int u = g * 4 + (c & 3);
    int colg = (c >> 2) * 512 + u;

    sv8 BH[16], BL[16];
    {
        const sv8* ph = (const sv8*)rkh + (size_t)g * 1024 + lane;
        const sv8* pl = (const sv8*)rkl + (size_t)g * 1024 + lane;
#pragma unroll
        for (int kt = 0; kt < 16; kt++) {
            BH[kt] = ph[kt * 64];
            BL[kt] = pl[kt * 64];
        }
    }
    float bv = bias[colg];
    int b0 = hf * 16 + lq * 4;               // global batch row base; +r
    float cst[4];
#pragma unroll
    for (int r = 0; r < 4; r++) cst[r] = cstate[(b0 + r) * 512 + u];
    const float* xzb = xz + ((size_t)(g * 64 + b0) * TCH) * 16 + c;
    int off_w = (cg * 64 + lq * 4 + 16 * (w >> 1)) * 8 + (w & 1) * 4;
    char*     hbx = hbuf + (size_t)hf * (NREG * REGB);
    uint32_t* rdx = rdy + (size_t)hf * (NREG * 64 * 16);   // 64 lines x 64B per region
    int slot = cg * 8 + w;                   // this wave's stamp slot

    for (int tl = 0; tl < TCH; tl++) {
        int t = gbase + tl;
        int reg = t & (NREG - 1), wreg = (t + 1) & (NREG - 1);
        const float* xzt = xzb + tl * 16;
        float xzv[4];
#pragma unroll
        for (int r = 0; r < 4; r++) xzv[r] = xzt[r * (TCH * 16)];

        // ---- stamp poll: lane l watches wave-slots 2l, 2l+1 (safe drain) ----
        {
            const uint32_t* rp = rdx + (size_t)(reg * 64 + lane) * 16;
            uint32_t want = (uint32_t)t;
            for (;;) {
                u32x2 v = load8_cc(rp);
                asm volatile("s_waitcnt vmcnt(0)" ::: "memory");
                __builtin_amdgcn_sched_barrier(0);
                if (__all((int)(v[0] >= want && v[1] >= want))) break;
            }
        }
        // ---- payload fetch (16KB group slice), exactly once ----
        const char* src = hbx + (size_t)reg * REGB + tid * 16;
        u32x4 hv[2];
#pragma unroll
        for (int i = 0; i < 2; i++) hv[i] = load16_cc(src + i * 8192);
        asm volatile("s_waitcnt vmcnt(0)" ::: "memory");
        __builtin_amdgcn_sched_barrier(0);
#pragma unroll
        for (int i = 0; i < 2; i++) *(u32x4*)&ls[i * 4096 + tid * 8] = hv[i];
        __syncthreads();   // (C) staging complete

        // ---- MFMA: 16 rows x 16 cols, K=512, hi+lo ----
        fv4 aH = (fv4){0.f, 0.f, 0.f, 0.f};
        fv4 aL = (fv4){0.f, 0.f, 0.f, 0.f};
#pragma unroll
        for (int half = 0; half < 2; half++) {
            sv8 af[8];
#pragma unroll
            for (int k8 = 0; k8 < 8; k8++)
                af[k8] = *(const sv8*)&ls[((half * 8 + k8) * 64 + lane) * 8];
#pragma unroll
            for (int k8 = 0; k8 < 8; k8++) {
                aH = __builtin_amdgcn_mfma_f32_16x16x32_bf16(af[k8], BH[half * 8 + k8], aH, 0, 0, 0);
                aL = __builtin_amdgcn_mfma_f32_16x16x32_bf16(af[k8], BL[half * 8 + k8], aL, 0, 0, 0);
            }
        }

        // ---- gates ----
        char* wdst = hbx + (size_t)wreg * REGB;
#pragma unroll
        for (int r = 0; r < 4; r++) {
            float z  = aH[r] + aL[r] + bv + xzv[r];
            float z2 = __shfl_xor(z, 4);
            float z3 = __shfl_xor(z, 8);
            float z4 = __shfl_xor(z, 12);
            float v1 = ftanh(z);
            float v2 = fsig(z2);
            float v3 = fsig(z3);
            float v4 = fsig(z4);
            cst[r] = v1 * v2 + v3 * cst[r];
            float hn = v4 * ftanh(cst[r]);
            uint32_t hbts = (uint32_t)f2bf(hn);
            int bsl = lane & 48;
            uint32_t h0 = __shfl(hbts, bsl);
            uint32_t h1 = __shfl(hbts, bsl + 1);
            uint32_t h2 = __shfl(hbts, bsl + 2);
            uint32_t h3 = __shfl(hbts, bsl + 3);
            if (c == 0) {
                u32x2 pk = (u32x2){h0 | (h1 << 16), h2 | (h3 << 16)};
                atom8_st(wdst + (size_t)(off_w + r * 8) * 2, pk);
            }
            if (t == TT - 1 && c < 4) hlast[(b0 + r) * 512 + u] = hn;
        }
        // ---- publish: own-wave drain, per-wave stamp (NO join barrier) ----
        asm volatile("s_waitcnt vmcnt(0)" ::: "memory");
        if (lane == 0)
            atom4_st(rdx + (size_t)(wreg * 64 + (slot >> 1)) * 16 + (slot & 1),
                     (uint32_t)(t + 1));
    }
    if (c < 4) {
#pragma unroll
        for (int r = 0; r < 4; r++) cstate[(b0 + r) * 512 + u] = cst[r];
    }
    asm volatile("s_waitcnt vmcnt(0)" ::: "memory");
}

// =====================================================================
// Phase 2 standalone (fallback path, small ws): grid 64 x 512.
// =====================================================================
__global__ __launch_bounds__(512, 2) void lstm_rec(
    const uint16_t* __restrict__ rkh, const uint16_t* __restrict__ rkl,
    const float* __restrict__ bias, const float* __restrict__ xz,
    char* __restrict__ hbuf, uint32_t* __restrict__ rdy,
    float* __restrict__ cstate, float* __restrict__ hlast, int gbase) {
    __shared__ __align__(16) uint16_t ls[8192];
    lstm_body(rkh, rkl, bias, xz, hbuf, rdy, cstate, hlast, gbase,
              ls, blockIdx.x, threadIdx.x);
}

// =====================================================================
// FUSED (big ws): blocks 0-63 = recurrence chunk k (4 groups x 16);
// blocks 64-255 = gemm for chunk k+1 (two 256-thr sub-WGs, 3 iters).
// =====================================================================
__global__ __launch_bounds__(512, 2) void fused_step(
    const uint16_t* __restrict__ rkh, const uint16_t* __restrict__ rkl,
    const float* __restrict__ bias, const float* __restrict__ xz_cur,
    char* __restrict__ hbuf, uint32_t* __restrict__ rdy,
    float* __restrict__ cstate, float* __restrict__ hlast, int gbase,
    const float* __restrict__ tx, int t0_next,
    const uint16_t* __restrict__ Bth, const uint16_t* __restrict__ Btl,
    float* __restrict__ xz_next) {
    __shared__ __align__(16) uint16_t shm[32768];   // 64KB, role-shared
    int bid = blockIdx.x, tid = threadIdx.x;
    if (bid < 64) {
        lstm_body(rkh, rkl, bias, xz_cur, hbuf, rdy, cstate, hlast, gbase,
                  shm, bid, tid);
    } else {
        if (t0_next < 0) return;            // last chunk: no next gemm
        int t256 = tid & 255, subwg = tid >> 8;
        uint16_t* sb = shm + subwg * 16384;  // 32KB per sub-WG
        int slot = (bid - 64) * 2 + subwg;   // 0..383
#pragma unroll 1
        for (int it = 0; it < 3; ++it) {
            int tile = slot + it * 384;
            int act = tile < 1024;
            int btile = (tile < 1024 ? tile : 0) >> 4;
            int n0 = ((tile < 1024 ? tile : 0) & 15) * 128;
            gemm_tile(tx, t0_next, Bth, Btl, xz_next, sb, t256, btile, n0, act);
        }
    }
}

// =====================================================================
// Phase 3: out = softmax(hlast @ fc_w + fc_b)   [64][4]
// =====================================================================
__global__ void final_out(const float* __restrict__ hlast, const float* __restrict__ fcw,
                          const float* __restrict__ fcb, float* __restrict__ out) {
    __shared__ float lg[256];
    int tid = threadIdx.x;
    int b = tid >> 2, o = tid & 3;
    float s = fcb[o];
    const float* hr = hlast + b * 512;
    for (int k = 0; k < 512; k++) s += hr[k] * fcw[k * 4 + o];
    lg[tid] = s;
    __syncthreads();
    float l0 = lg[b * 4 + 0], l1 = lg[b * 4 + 1], l2 = lg[b * 4 + 2], l3 = lg[b * 4 + 3];
    float m = fmaxf(fmaxf(l0, l1), fmaxf(l2, l3));
    float sum = expf(l0 - m) + expf(l1 - m) + expf(l2 - m) + expf(l3 - m);
    out[tid] = expf(s - m) / sum;
}

// =====================================================================
extern "C" void kernel_launch(void* const* d_in, const int* in_sizes, int n_in,
                              void* d_out, int out_size, void* d_ws, size_t ws_size,
                              hipStream_t stream) {
    const float* tx   = (const float*)d_in[0];
    const float* kern = (const float*)d_in[1];
    const float* rk   = (const float*)d_in[2];
    const float* bias = (const float*)d_in[3];
    const float* fcw  = (const float*)d_in[4];
    const float* fcb  = (const float*)d_in[5];
    float* out = (float*)d_out;

    char* ws = (char*)d_ws;
    size_t off = 0;
    auto alloc = [&](size_t bytes) -> void* {
        void* p = ws + off;
        off += (bytes + 255) & ~(size_t)255;
        return p;
    };
    float*    xz0    = (float*)alloc((size_t)128 * 64 * TCH * 16 * 4);   // 67 MB
    uint16_t* Bth    = (uint16_t*)alloc((size_t)NN * DD * 2);            // 2 MB
    uint16_t* Btl    = (uint16_t*)alloc((size_t)NN * DD * 2);            // 2 MB
    uint16_t* rkh    = (uint16_t*)alloc((size_t)128 * 16 * 64 * 8 * 2);  // 2 MB
    uint16_t* rkl    = (uint16_t*)alloc((size_t)128 * 16 * 64 * 8 * 2);  // 2 MB
    char*     hbuf   = (char*)alloc((size_t)NG * NREG * REGB);           // 512 KB
    uint32_t* rdy    = (uint32_t*)alloc((size_t)NG * NREG * 64 * 16 * 4);// 128 KB
    float*    cstate = (float*)alloc(64 * 512 * 4);                      // 128 KB
    float*    hlast  = (float*)alloc(64 * 512 * 4);                      // 128 KB
    size_t small_need = off;
    float*    xz1    = (float*)alloc((size_t)128 * 64 * TCH * 16 * 4);   // +67 MB
    size_t big_need = off;
    int big = (ws_size >= big_need);
    if (ws_size < small_need) big = 0;   // defensive

    // region 0 of ALL group rings: h_{-1} = 0
    for (int q = 0; q < NG; ++q)
        hipMemsetAsync(hbuf + (size_t)q * NREG * REGB, 0, REGB, stream);
    hipMemsetAsync(rdy, 0, (size_t)NG * NREG * 64 * 16 * 4, stream);
    hipMemsetAsync(cstate, 0, 64 * 512 * 4, stream);

    prep_split_b<<<4096, 256, 0, stream>>>(kern, Bth, Btl);
    prep_rk<<<4096, 256, 0, stream>>>(rk, rkh, rkl);

    if (big) {
        gemm_xz<<<1024, 256, 0, stream>>>(tx, 0, Bth, Btl, xz0);
        for (int k = 0; k < NCHUNK; ++k) {
            const float* xzc = (k & 1) ? xz1 : xz0;
            float*       xzn = (k & 1) ? xz0 : xz1;
            fused_step<<<256, 512, 0, stream>>>(rkh, rkl, bias, xzc, hbuf, rdy,
                                                cstate, hlast, k * TCH,
                                                tx, (k < NCHUNK - 1) ? (k + 1) * TCH : -1,
                                                Bth, Btl, xzn);
        }
    } else {
        for (int k = 0; k < NCHUNK; ++k) {
            gemm_xz<<<1024, 256, 0, stream>>>(tx, k * TCH, Bth, Btl, xz0);
            lstm_rec<<<64, 512, 0, stream>>>(rkh, rkl, bias, xz0, hbuf, rdy,
                                             cstate, hlast, k * TCH);
        }
    }
    final_out<<<1, 256, 0, stream>>>(hlast, fcw, fcb, out);
}

// Round 19
// 4497.640 us; speedup vs baseline: 1.3450x; 1.3450x over previous
//
#include <hip/hip_runtime.h>
#include <stdint.h>

// ---------- types ----------
typedef short sv8 __attribute__((ext_vector_type(8)));      // 8 x bf16 raw
typedef float fv4 __attribute__((ext_vector_type(4)));      // MFMA acc
typedef uint32_t u32x4 __attribute__((ext_vector_type(4))); // asm operand
typedef uint32_t u32x2 __attribute__((ext_vector_type(2))); // asm operand

__device__ __forceinline__ uint16_t f2bf(float f) {
    uint32_t u = __builtin_bit_cast(uint32_t, f);
    u += 0x7FFFu + ((u >> 16) & 1u);
    return (uint16_t)(u >> 16);
}
__device__ __forceinline__ float bf2f(uint16_t h) {
    uint32_t u = ((uint32_t)h) << 16;
    return __builtin_bit_cast(float, u);
}
__device__ __forceinline__ void split4(float4 f, ushort4& h, ushort4& l) {
    h.x = f2bf(f.x); l.x = f2bf(f.x - bf2f(h.x));
    h.y = f2bf(f.y); l.y = f2bf(f.y - bf2f(h.y));
    h.z = f2bf(f.z); l.z = f2bf(f.z - bf2f(h.z));
    h.w = f2bf(f.w); l.w = f2bf(f.w - bf2f(h.w));
}
// fast gates (finite-in -> finite-out)
__device__ __forceinline__ float fsig(float x)  { return 1.f / (1.f + __expf(-x)); }
__device__ __forceinline__ float ftanh(float x) { return 1.f - 2.f / (__expf(2.f * x) + 1.f); }

// coherent (MALL-point) loads
__device__ __forceinline__ u32x4 load16_cc(const void* p) {
    u32x4 r;
    asm volatile("global_load_dwordx4 %0, %1, off sc0 sc1" : "=v"(r) : "v"(p) : "memory");
    return r;
}
__device__ __forceinline__ uint32_t load4_cc(const void* p) {
    uint32_t r;
    asm volatile("global_load_dword %0, %1, off sc0 sc1" : "=v"(r) : "v"(p) : "memory");
    return r;
}
// atomic stores: performed AT the MALL -> fast global visibility
__device__ __forceinline__ void atom8_st(void* p, u32x2 v) {
    asm volatile("global_atomic_swap_x2 %0, %1, off" :: "v"(p), "v"(v) : "memory");
}
__device__ __forceinline__ void atom4_st(void* p, uint32_t v) {
    asm volatile("global_atomic_swap %0, %1, off" :: "v"(p), "v"(v) : "memory");
}

// ---------- sizes ----------
#define TT     1024
#define DD     512
#define NN     2048
#define TCH    128           // timesteps per chunk
#define NCHUNK 8
#define NREG   8             // h region ring (16KB regions, per group)
#define RSTRIDE 16           // rdy stamp stride in u32 (64B line per producer)
#define REGB   16384         // region bytes (16 rows x 512 u x 2B)
#define NG     4             // row groups
#define GW     16            // WGs per group

// =====================================================================
// Prep: kernel [512][2048] fp32 -> transposed bf16 hi/lo  BT[2048][512]
// =====================================================================
__global__ void prep_split_b(const float* __restrict__ kern,
                             uint16_t* __restrict__ bth, uint16_t* __restrict__ btl) {
    int tid = blockIdx.x * 256 + threadIdx.x;
    if (tid >= DD * NN) return;
    int k = tid >> 11;
    int n = tid & (NN - 1);
    float v = kern[tid];
    uint16_t h = f2bf(v);
    bth[n * DD + k] = h;
    btl[n * DD + k] = f2bf(v - bf2f(h));
}

// =====================================================================
// Prep: recurrent_kernel -> per-lane MFMA B-fragment order, split hi/lo
// =====================================================================
__global__ void prep_rk(const float* __restrict__ rk,
                        uint16_t* __restrict__ rkh, uint16_t* __restrict__ rkl) {
    int tid = blockIdx.x * 256 + threadIdx.x;
    if (tid >= 128 * 16 * 64 * 8) return;
    int j = tid & 7, lane = (tid >> 3) & 63, kt = (tid >> 9) & 15, g = tid >> 13;
    int lq = lane >> 4, c = lane & 15;
    int k = kt * 32 + lq * 8 + j;
    int colg = (c >> 2) * 512 + g * 4 + (c & 3);
    float v = rk[(size_t)k * NN + colg];
    uint16_t h = f2bf(v);
    rkh[tid] = h;
    rkl[tid] = f2bf(v - bf2f(h));
}

// =====================================================================
// GEMM tile body (shared by gemm_xz and fused gemm role).
// =====================================================================
__device__ __forceinline__ void gemm_tile(
    const float* __restrict__ tx, int t0,
    const uint16_t* __restrict__ Bth, const uint16_t* __restrict__ Btl,
    float* __restrict__ xz, uint16_t* sb, int t256, int btile, int n0, int act) {
    int lane = t256 & 63, w = t256 >> 6;
    int wm = (w >> 1) * 64, wn = (w & 1) * 64;
    int srow = t256 >> 1, scol = (t256 & 1) * 16;
    fv4 acc[4][4];
#pragma unroll
    for (int q = 0; q < 4; q++)
#pragma unroll
        for (int r = 0; r < 4; r++) acc[q][r] = (fv4){0.f, 0.f, 0.f, 0.f};

    const float* abase = tx + ((size_t)btile * TT + t0 + srow) * DD + scol;

    for (int k0 = 0; k0 < DD; k0 += 32) {
        float4 f0, f1, f2, f3;
        uint4 b0, b1, c0, c1;
        if (act) {
            const float4* A4 = (const float4*)(abase + k0);
            f0 = A4[0]; f1 = A4[1]; f2 = A4[2]; f3 = A4[3];
            const uint16_t* pb  = Bth + (size_t)(n0 + srow) * DD + k0 + scol;
            const uint16_t* pbl = Btl + (size_t)(n0 + srow) * DD + k0 + scol;
            b0 = *(const uint4*)pb;  b1 = *(const uint4*)(pb + 8);
            c0 = *(const uint4*)pbl; c1 = *(const uint4*)(pbl + 8);
        }
        __syncthreads();
        if (act) {
            union { ushort4 v4[4]; uint4 q[2]; } H, L;
            split4(f0, H.v4[0], L.v4[0]);
            split4(f1, H.v4[1], L.v4[1]);
            split4(f2, H.v4[2], L.v4[2]);
            split4(f3, H.v4[3], L.v4[3]);
            *(uint4*)&sb[srow * 32 + scol]            = H.q[0];
            *(uint4*)&sb[srow * 32 + scol + 8]        = H.q[1];
            *(uint4*)&sb[4096 + srow * 32 + scol]     = L.q[0];
            *(uint4*)&sb[4096 + srow * 32 + scol + 8] = L.q[1];
            *(uint4*)&sb[8192 + srow * 32 + scol]     = b0;
            *(uint4*)&sb[8192 + srow * 32 + scol + 8] = b1;
            *(uint4*)&sb[12288 + srow * 32 + scol]    = c0;
            *(uint4*)&sb[12288 + srow * 32 + scol + 8]= c1;
        }
        __syncthreads();
        sv8 ah[4], al[4], bh[4], bl[4];
#pragma unroll
        for (int q = 0; q < 4; q++) {
            int ra = (wm + q * 16 + (lane & 15)) * 32 + (lane >> 4) * 8;
            ah[q] = *(const sv8*)&sb[ra];
            al[q] = *(const sv8*)&sb[4096 + ra];
        }
#pragma unroll
        for (int r = 0; r < 4; r++) {
            int rb = (wn + r * 16 + (lane & 15)) * 32 + (lane >> 4) * 8;
            bh[r] = *(const sv8*)&sb[8192 + rb];
            bl[r] = *(const sv8*)&sb[12288 + rb];
        }
#pragma unroll
        for (int q = 0; q < 4; q++)
#pragma unroll
            for (int r = 0; r < 4; r++) {
                acc[q][r] = __builtin_amdgcn_mfma_f32_16x16x32_bf16(ah[q], bh[r], acc[q][r], 0, 0, 0);
                acc[q][r] = __builtin_amdgcn_mfma_f32_16x16x32_bf16(ah[q], bl[r], acc[q][r], 0, 0, 0);
                acc[q][r] = __builtin_amdgcn_mfma_f32_16x16x32_bf16(al[q], bh[r], acc[q][r], 0, 0, 0);
            }
    }
    if (act) {
#pragma unroll
        for (int q = 0; q < 4; q++)
#pragma unroll
            for (int r = 0; r < 4; r++) {
                int tl0 = wm + q * 16 + ((lane >> 4) * 4);
                int ncol = n0 + wn + r * 16 + (lane & 15);
                int gate = ncol >> 9, uu = ncol & 511;
                int cil = gate * 4 + (uu & 3);
                int g = uu >> 2;
#pragma unroll
                for (int e = 0; e < 4; e++) {
                    size_t idx = (((size_t)(g * 64 + btile) * TCH + (tl0 + e)) << 4) + cil;
                    xz[idx] = acc[q][r][e];
                }
            }
    }
}

// =====================================================================
// Phase 1 standalone: xz for one chunk.  Grid 1024 x 256.
// =====================================================================
__global__ __launch_bounds__(256, 2) void gemm_xz(
    const float* __restrict__ tx, int t0,
    const uint16_t* __restrict__ Bth, const uint16_t* __restrict__ Btl,
    float* __restrict__ xz) {
    __shared__ __align__(16) uint16_t sb[16384];   // 32KB
    gemm_tile(tx, t0, Bth, Btl, xz, sb, threadIdx.x,
              blockIdx.x >> 4, (blockIdx.x & 15) * 128, 1);
}

// =====================================================================
// LSTM recurrence body, 4 independent row-groups (r16 PROVEN BEST):
// wg in [0,64): hf = wg>>4 (16-row group), cg = wg&15 (owns 32 u).
// 8 waves: wave w owns u-quad g = cg*8+w; all waves share the group's
// single 16-row tile.  Per wave: 16 rows x 16 z-cols, K=512, hi+lo.
// Each group exchanges ONLY its 16KB h-slice among its 16 WGs.
// Transport: atomic-swap + per-producer 64B stamp lines + WG join.
// =====================================================================
__device__ __forceinline__ void lstm_body(
    const uint16_t* __restrict__ rkh, const uint16_t* __restrict__ rkl,
    const float* __restrict__ bias, const float* __restrict__ xz,
    char* __restrict__ hbuf, uint32_t* __restrict__ rdy,
    float* __restrict__ cstate, float* __restrict__ hlast, int gbase,
    uint16_t* ls /* 8192 u16 = 16KB */, int wg, int tid) {
    int hf = wg >> 4, cg = wg & 15;
    int lane = tid & 63, w = tid >> 6;      // 8 waves
    int c = lane & 15, lq = lane >> 4;
    int g = cg * 8 + w;                      // u-quad 0..127
    int u = g * 4 + (c & 3);
    int colg = (c >> 2) * 512 + u;

    sv8 BH[16], BL[16];
    {
        const sv8* ph = (const sv8*)rkh + (size_t)g * 1024 + lane;
        const sv8* pl = (const sv8*)rkl + (size_t)g * 1024 + lane;
#pragma unroll
        for (int kt = 0; kt < 16; kt++) {
            BH[kt] = ph[kt * 64];
            BL[kt] = pl[kt * 64];
        }
    }
    float bv = bias[colg];
    int b0 = hf * 16 + lq * 4;               // global batch row base; +r
    float cst[4];
#pragma unroll
    for (int r = 0; r < 4; r++) cst[r] = cstate[(b0 + r) * 512 + u];
    const float* xzb = xz + ((size_t)(g * 64 + b0) * TCH) * 16 + c;
    int off_w = (cg * 64 + lq * 4 + 16 * (w >> 1)) * 8 + (w & 1) * 4;
    char*     hbx = hbuf + (size_t)hf * (NREG * REGB);
    uint32_t* rdx = rdy + hf * (NREG * GW * RSTRIDE);
    int own = ((lane & 15) == cg) ? 1 : 0;

    for (int tl = 0; tl < TCH; tl++) {
        int t = gbase + tl;
        int reg = t & (NREG - 1), wreg = (t + 1) & (NREG - 1);
        const float* xzt = xzb + tl * 16;
        float xzv[4];
#pragma unroll
        for (int r = 0; r < 4; r++) xzv[r] = xzt[r * (TCH * 16)];

        // ---- stamp poll: lane watches producer (lane&15), own skipped ----
        {
            const uint32_t* rp = rdx + (size_t)(reg * GW + (lane & 15)) * RSTRIDE;
            uint32_t want = (uint32_t)t;
            for (;;) {
                uint32_t v = load4_cc(rp);
                asm volatile("s_waitcnt vmcnt(0)" ::: "memory");
                if (__all(own | (int)(v >= want))) break;
            }
        }
        // ---- payload fetch (16KB group slice), exactly once ----
        const char* src = hbx + (size_t)reg * REGB + tid * 16;
        u32x4 hv[2];
#pragma unroll
        for (int i = 0; i < 2; i++) hv[i] = load16_cc(src + i * 8192);
        asm volatile("s_waitcnt vmcnt(0)" ::: "memory");
        __builtin_amdgcn_sched_barrier(0);
#pragma unroll
        for (int i = 0; i < 2; i++) *(u32x4*)&ls[i * 4096 + tid * 8] = hv[i];
        __syncthreads();   // (C) staging complete

        // ---- MFMA: 16 rows x 16 cols, K=512, hi+lo ----
        fv4 aH = (fv4){0.f, 0.f, 0.f, 0.f};
        fv4 aL = (fv4){0.f, 0.f, 0.f, 0.f};
#pragma unroll
        for (int half = 0; half < 2; half++) {
            sv8 af[8];
#pragma unroll
            for (int k8 = 0; k8 < 8; k8++)
                af[k8] = *(const sv8*)&ls[((half * 8 + k8) * 64 + lane) * 8];
#pragma unroll
            for (int k8 = 0; k8 < 8; k8++) {
                aH = __builtin_amdgcn_mfma_f32_16x16x32_bf16(af[k8], BH[half * 8 + k8], aH, 0, 0, 0);
                aL = __builtin_amdgcn_mfma_f32_16x16x32_bf16(af[k8], BL[half * 8 + k8], aL, 0, 0, 0);
            }
        }

        // ---- gates ----
        char* wdst = hbx + (size_t)wreg * REGB;
#pragma unroll
        for (int r = 0; r < 4; r++) {
            float z  = aH[r] + aL[r] + bv + xzv[r];
            float z2 = __shfl_xor(z, 4);
            float z3 = __shfl_xor(z, 8);
            float z4 = __shfl_xor(z, 12);
            float v1 = ftanh(z);
            float v2 = fsig(z2);
            float v3 = fsig(z3);
            float v4 = fsig(z4);
            cst[r] = v1 * v2 + v3 * cst[r];
            float hn = v4 * ftanh(cst[r]);
            uint32_t hbts = (uint32_t)f2bf(hn);
            int bsl = lane & 48;
            uint32_t h0 = __shfl(hbts, bsl);
            uint32_t h1 = __shfl(hbts, bsl + 1);
            uint32_t h2 = __shfl(hbts, bsl + 2);
            uint32_t h3 = __shfl(hbts, bsl + 3);
            if (c == 0) {
                u32x2 pk = (u32x2){h0 | (h1 << 16), h2 | (h3 << 16)};
                atom8_st(wdst + (size_t)(off_w + r * 8) * 2, pk);
            }
            if (t == TT - 1 && c < 4) hlast[(b0 + r) * 512 + u] = hn;
        }
        // ---- publish: drain atomics, join, stamp ----
        asm volatile("s_waitcnt vmcnt(0)" ::: "memory");
        __syncthreads();   // (A)
        if (tid == 0)
            atom4_st(rdx + (size_t)(wreg * GW + cg) * RSTRIDE, (uint32_t)(t + 1));
    }
    if (c < 4) {
#pragma unroll
        for (int r = 0; r < 4; r++) cstate[(b0 + r) * 512 + u] = cst[r];
    }
    asm volatile("s_waitcnt vmcnt(0)" ::: "memory");
}

// =====================================================================
// Phase 2 standalone (fallback path, small ws): grid 64 x 512.
// =====================================================================
__global__ __launch_bounds__(512, 2) void lstm_rec(
    const uint16_t* __restrict__ rkh, const uint16_t* __restrict__ rkl,
    const float* __restrict__ bias, const float* __restrict__ xz,
    char* __restrict__ hbuf, uint32_t* __restrict__ rdy,
    float* __restrict__ cstate, float* __restrict__ hlast, int gbase) {
    __shared__ __align__(16) uint16_t ls[8192];
    lstm_body(rkh, rkl, bias, xz, hbuf, rdy, cstate, hlast, gbase,
              ls, blockIdx.x, threadIdx.x);
}

// =====================================================================
// FUSED (big ws): blocks 0-63 = recurrence chunk k (4 groups x 16);
// blocks 64-255 = gemm for chunk k+1 (two 256-thr sub-WGs, 3 iters).
// =====================================================================
__global__ __launch_bounds__(512, 2) void fused_step(
    const uint16_t* __restrict__ rkh, const uint16_t* __restrict__ rkl,
    const float* __restrict__ bias, const float* __restrict__ xz_cur,
    char* __restrict__ hbuf, uint32_t* __restrict__ rdy,
    float* __restrict__ cstate, float* __restrict__ hlast, int gbase,
    const float* __restrict__ tx, int t0_next,
    const uint16_t* __restrict__ Bth, const uint16_t* __restrict__ Btl,
    float* __restrict__ xz_next) {
    __shared__ __align__(16) uint16_t shm[32768];   // 64KB, role-shared
    int bid = blockIdx.x, tid = threadIdx.x;
    if (bid < 64) {
        lstm_body(rkh, rkl, bias, xz_cur, hbuf, rdy, cstate, hlast, gbase,
                  shm, bid, tid);
    } else {
        if (t0_next < 0) return;            // last chunk: no next gemm
        int t256 = tid & 255, subwg = tid >> 8;
        uint16_t* sb = shm + subwg * 16384;  // 32KB per sub-WG
        int slot = (bid - 64) * 2 + subwg;   // 0..383
#pragma unroll 1
        for (int it = 0; it < 3; ++it) {
            int tile = slot + it * 384;
            int act = tile < 1024;
            int btile = (tile < 1024 ? tile : 0) >> 4;
            int n0 = ((tile < 1024 ? tile : 0) & 15) * 128;
            gemm_tile(tx, t0_next, Bth, Btl, xz_next, sb, t256, btile, n0, act);
        }
    }
}

// =====================================================================
// Phase 3: out = softmax(hlast @ fc_w + fc_b)   [64][4]
// =====================================================================
__global__ void final_out(const float* __restrict__ hlast, const float* __restrict__ fcw,
                          const float* __restrict__ fcb, float* __restrict__ out) {
    __shared__ float lg[256];
    int tid = threadIdx.x;
    int b = tid >> 2, o = tid & 3;
    float s = fcb[o];
    const float* hr = hlast + b * 512;
    for (int k = 0; k < 512; k++) s += hr[k] * fcw[k * 4 + o];
    lg[tid] = s;
    __syncthreads();
    float l0 = lg[b * 4 + 0], l1 = lg[b * 4 + 1], l2 = lg[b * 4 + 2], l3 = lg[b * 4 + 3];
    float m = fmaxf(fmaxf(l0, l1), fmaxf(l2, l3));
    float sum = expf(l0 - m) + expf(l1 - m) + expf(l2 - m) + expf(l3 - m);
    out[tid] = expf(s - m) / sum;
}

// =====================================================================
extern "C" void kernel_launch(void* const* d_in, const int* in_sizes, int n_in,
                              void* d_out, int out_size, void* d_ws, size_t ws_size,
                              hipStream_t stream) {
    const float* tx   = (const float*)d_in[0];
    const float* kern = (const float*)d_in[1];
    const float* rk   = (const float*)d_in[2];
    const float* bias = (const float*)d_in[3];
    const float* fcw  = (const float*)d_in[4];
    const float* fcb  = (const float*)d_in[5];
    float* out = (float*)d_out;

    char* ws = (char*)d_ws;
    size_t off = 0;
    auto alloc = [&](size_t bytes) -> void* {
        void* p = ws + off;
        off += (bytes + 255) & ~(size_t)255;
        return p;
    };
    float*    xz0    = (float*)alloc((size_t)128 * 64 * TCH * 16 * 4);   // 67 MB
    uint16_t* Bth    = (uint16_t*)alloc((size_t)NN * DD * 2);            // 2 MB
    uint16_t* Btl    = (uint16_t*)alloc((size_t)NN * DD * 2);            // 2 MB
    uint16_t* rkh    = (uint16_t*)alloc((size_t)128 * 16 * 64 * 8 * 2);  // 2 MB
    uint16_t* rkl    = (uint16_t*)alloc((size_t)128 * 16 * 64 * 8 * 2);  // 2 MB
    char*     hbuf   = (char*)alloc((size_t)NG * NREG * REGB);           // 512 KB
    uint32_t* rdy    = (uint32_t*)alloc((size_t)NG * NREG * GW * RSTRIDE * 4); // 32 KB
    float*    cstate = (float*)alloc(64 * 512 * 4);                      // 128 KB
    float*    hlast  = (float*)alloc(64 * 512 * 4);                      // 128 KB
    size_t small_need = off;
    float*    xz1    = (float*)alloc((size_t)128 * 64 * TCH * 16 * 4);   // +67 MB
    size_t big_need = off;
    int big = (ws_size >= big_need);
    if (ws_size < small_need) big = 0;   // defensive

    // region 0 of ALL group rings: h_{-1} = 0
    for (int q = 0; q < NG; ++q)
        hipMemsetAsync(hbuf + (size_t)q * NREG * REGB, 0, REGB, stream);
    hipMemsetAsync(rdy, 0, (size_t)NG * NREG * GW * RSTRIDE * 4, stream);
    hipMemsetAsync(cstate, 0, 64 * 512 * 4, stream);

    prep_split_b<<<4096, 256, 0, stream>>>(kern, Bth, Btl);
    prep_rk<<<4096, 256, 0, stream>>>(rk, rkh, rkl);

    if (big) {
        gemm_xz<<<1024, 256, 0, stream>>>(tx, 0, Bth, Btl, xz0);
        for (int k = 0; k < NCHUNK; ++k) {
            const float* xzc = (k & 1) ? xz1 : xz0;
            float*       xzn = (k & 1) ? xz0 : xz1;
            fused_step<<<256, 512, 0, stream>>>(rkh, rkl, bias, xzc, hbuf, rdy,
                                                cstate, hlast, k * TCH,
                                                tx, (k < NCHUNK - 1) ? (k + 1) * TCH : -1,
                                                Bth, Btl, xzn);
        }
    } else {
        for (int k = 0; k < NCHUNK; ++k) {
            gemm_xz<<<1024, 256, 0, stream>>>(tx, k * TCH, Bth, Btl, xz0);
            lstm_rec<<<64, 512, 0, stream>>>(rkh, rkl, bias, xz0, hbuf, rdy,
                                             cstate, hlast, k * TCH);
        }
    }
    final_out<<<1, 256, 0, stream>>>(hlast, fcw, fcb, out);
}